// Round 1
// baseline (241.412 us; speedup 1.0000x reference)
//
#include <hip/hip_runtime.h>

// GRAPE step collapse: all steps are exp(-i*theta_k*X) about the same axis,
// so the scan == single rotation by Theta = sum(a_k) * (DT/2).
//   out_real0 = c*r0 + s*i1    out_imag0 = c*i0 - s*r1
//   out_real1 = c*r1 + s*i0    out_imag1 = c*i1 - s*r0
// Output layout (stack of real/imag of [2,B]): [real0 | real1 | imag0 | imag1],
// each segment B floats. Pure streaming kernel: 128 MiB in + 128 MiB out.

__global__ __launch_bounds__(256) void grape_kernel(
    const float* __restrict__ amps, int nsteps,
    const float* __restrict__ sreal, const float* __restrict__ simag,
    float* __restrict__ out, long long B) {
    // Theta is wave-uniform; 20 cached loads, negligible cost.
    float theta = 0.0f;
    for (int k = 0; k < nsteps; ++k) theta += amps[k];
    theta *= (1.0f / (float)nsteps) * 0.5f;  // DT/2 with GATE_TIME=1.0
    float c = cosf(theta);
    float s = sinf(theta);

    long long idx = (long long)blockIdx.x * blockDim.x + threadIdx.x;
    long long j = idx * 4;  // 4 columns per thread (float4)
    if (j + 3 >= B + 3) return;  // guard (B divisible by 4 in practice)
    if (j >= B) return;

    const float4 r0 = *(const float4*)(sreal + j);
    const float4 r1 = *(const float4*)(sreal + B + j);
    const float4 i0 = *(const float4*)(simag + j);
    const float4 i1 = *(const float4*)(simag + B + j);

    float4 or0, or1, oi0, oi1;
    or0.x = c * r0.x + s * i1.x;  or0.y = c * r0.y + s * i1.y;
    or0.z = c * r0.z + s * i1.z;  or0.w = c * r0.w + s * i1.w;

    or1.x = c * r1.x + s * i0.x;  or1.y = c * r1.y + s * i0.y;
    or1.z = c * r1.z + s * i0.z;  or1.w = c * r1.w + s * i0.w;

    oi0.x = c * i0.x - s * r1.x;  oi0.y = c * i0.y - s * r1.y;
    oi0.z = c * i0.z - s * r1.z;  oi0.w = c * i0.w - s * r1.w;

    oi1.x = c * i1.x - s * r0.x;  oi1.y = c * i1.y - s * r0.y;
    oi1.z = c * i1.z - s * r0.z;  oi1.w = c * i1.w - s * r0.w;

    *(float4*)(out + j)           = or0;
    *(float4*)(out + B + j)       = or1;
    *(float4*)(out + 2 * B + j)   = oi0;
    *(float4*)(out + 3 * B + j)   = oi1;
}

extern "C" void kernel_launch(void* const* d_in, const int* in_sizes, int n_in,
                              void* d_out, int out_size, void* d_ws, size_t ws_size,
                              hipStream_t stream) {
    const float* amps  = (const float*)d_in[0];
    const float* sreal = (const float*)d_in[1];
    const float* simag = (const float*)d_in[2];
    float* out = (float*)d_out;

    int nsteps = in_sizes[0];
    long long B = (long long)in_sizes[1] / 2;  // state_real is [2, B]

    long long nthreads = (B + 3) / 4;
    int block = 256;
    long long grid = (nthreads + block - 1) / block;

    grape_kernel<<<(dim3)(unsigned)grid, block, 0, stream>>>(
        amps, nsteps, sreal, simag, out, B);
}